// Round 4
// baseline (39.741 us; speedup 1.0000x reference)
//
#include <hip/hip_runtime.h>

#define NCOLORS 10
#define EPS 1e-8f
#define HW 4096
#define S_DIM 16
#define WAVES 8
#define THREADS 512
#define BK 512                    // K per outer iteration
#define NITER (HW / BK)           // 8

typedef __bf16 bf16x4 __attribute__((ext_vector_type(4)));
typedef __bf16 bf16x8 __attribute__((ext_vector_type(8)));
typedef float  f32x4  __attribute__((ext_vector_type(4)));

// LDS layout (32 KB total):
//   [0      , 16384) : bf16 tile [16 rows][512 k], XOR-swizzled; reused as red[8][256] f32 in epilogue
//   [16384  , 32768) : grids[b] staged as int32 [4096]; tail reused for ent16[16] in epilogue

__global__ __launch_bounds__(THREADS, 6)   // 3 blocks/CU -> 24 waves/CU
void color_entropy_mfma(const float* __restrict__ attn,   // [B, S, HW]
                        const int* __restrict__ grids,    // [B, HW]
                        float* __restrict__ out,          // [1]
                        float inv_BS)
{
    const int b    = blockIdx.x;
    const int tid  = threadIdx.x;
    const int lane = tid & 63;
    const int wave = tid >> 6;      // 0..7
    const int sc   = lane & 15;     // A-row (s) AND one-hot col (color)
    const int grp  = lane >> 4;     // k sub-group within 32-wide K tile

    __shared__ __align__(16) unsigned char smem[32768];
    int* grids_l = (int*)(smem + 16384);

    // ---- stage grids[b] (16 KB, coalesced int4) ----
    {
        const int4* g4 = (const int4*)(grids + (size_t)b * HW);
        int4* gl4 = (int4*)grids_l;
        gl4[tid]       = g4[tid];
        gl4[tid + 512] = g4[tid + 512];
    }

    // per-thread staging row/col (contiguous: 128 threads cover one 512-f32 row)
    const int st_row_base = tid >> 7;        // 0..3
    const int st_col4     = tid & 127;       // float4 index within row
    const float* aRow[4];
#pragma unroll
    for (int j = 0; j < 4; ++j)
        aRow[j] = attn + ((size_t)b * S_DIM + (j * 4 + st_row_base)) * HW + st_col4 * 4;

    const __bf16 ONE = (__bf16)1.0f;
    const __bf16 ZER = (__bf16)0.0f;

    f32x4 acc = {0.f, 0.f, 0.f, 0.f};
    float4 ra[4], rb[4];

#pragma unroll
    for (int j = 0; j < 4; ++j) ra[j] = *(const float4*)(aRow[j] + 0 * BK);

    auto step = [&](float4 (&cur)[4], float4 (&nxt)[4], int i) {
        if (i > 0) __syncthreads();          // tile i-1 fully consumed
        // write cur tile to LDS (cvt f32->bf16, XOR-swizzled, 2-way banks = free)
#pragma unroll
        for (int j = 0; j < 4; ++j) {
            const int row = j * 4 + st_row_base;
            unsigned byte = (unsigned)(row * 1024 + st_col4 * 8)
                          ^ ((unsigned)(row & 7) << 4);
            float4 v = cur[j];
            bf16x4 h;
            h[0] = (__bf16)v.x; h[1] = (__bf16)v.y;
            h[2] = (__bf16)v.z; h[3] = (__bf16)v.w;
            *(bf16x4*)(smem + byte) = h;
        }
        // issue next tile's loads early (in flight across the MFMA phase)
        if (i + 1 < NITER) {
#pragma unroll
            for (int j = 0; j < 4; ++j)
                nxt[j] = *(const float4*)(aRow[j] + (size_t)(i + 1) * BK);
        }
        __syncthreads();                     // tile i ready
        // MFMA phase: wave owns K slice [wave*64, wave*64+64) of this tile
#pragma unroll
        for (int ks = 0; ks < 2; ++ks) {
            const int kw = wave * 64 + ks * 32;
            unsigned byte = (unsigned)(sc * 1024 + (kw + grp * 8) * 2)
                          ^ ((unsigned)(sc & 7) << 4);
            bf16x8 a = *(const bf16x8*)(smem + byte);     // conflict-free (swizzled)
            const int* gp = grids_l + i * BK + kw + grp * 8;
            const int4 g0 = *(const int4*)gp;             // broadcast reads
            const int4 g1 = *(const int4*)(gp + 4);
            bf16x8 oh;
            oh[0] = (g0.x == sc) ? ONE : ZER;
            oh[1] = (g0.y == sc) ? ONE : ZER;
            oh[2] = (g0.z == sc) ? ONE : ZER;
            oh[3] = (g0.w == sc) ? ONE : ZER;
            oh[4] = (g1.x == sc) ? ONE : ZER;
            oh[5] = (g1.y == sc) ? ONE : ZER;
            oh[6] = (g1.z == sc) ? ONE : ZER;
            oh[7] = (g1.w == sc) ? ONE : ZER;
            acc = __builtin_amdgcn_mfma_f32_16x16x32_bf16(a, oh, acc, 0, 0, 0);
        }
    };

#pragma unroll
    for (int i = 0; i < NITER; i += 2) {     // static reg-set alternation (rule #20)
        step(ra, rb, i);
        step(rb, ra, i + 1);
    }

    // ---- epilogue: reduce 8 partial C tiles, entropy, atomic ----
    __syncthreads();                          // tile & grids now dead
    float* red = (float*)smem;                // [8][256] = 8 KB (over tile region)
#pragma unroll
    for (int j = 0; j < 4; ++j)
        red[wave * 256 + (grp * 4 + j) * 16 + sc] = acc[j];
    __syncthreads();

    if (tid < 256) {
        float s = 0.f;
#pragma unroll
        for (int w = 0; w < WAVES; ++w) s += red[w * 256 + tid];
        red[tid] = s;
    }
    __syncthreads();

    float* ent16 = (float*)(smem + 16384);    // over grids region
    if (tid < S_DIM) {
        float bins[NCOLORS];
        float tot = 0.f;
#pragma unroll
        for (int c = 0; c < NCOLORS; ++c) {
            bins[c] = red[tid * 16 + c];
            tot += bins[c];
        }
        const float inv = 1.0f / (tot + EPS);
        float e = 0.f;
#pragma unroll
        for (int c = 0; c < NCOLORS; ++c) {
            const float p = bins[c] * inv;
            e -= p * __logf(p + EPS);
        }
        ent16[tid] = e;
    }
    __syncthreads();

    if (tid == 0) {
        float s = 0.f;
#pragma unroll
        for (int i = 0; i < S_DIM; ++i) s += ent16[i];
        atomicAdd(out, s * inv_BS);
    }
}

extern "C" void kernel_launch(void* const* d_in, const int* in_sizes, int n_in,
                              void* d_out, int out_size, void* d_ws, size_t ws_size,
                              hipStream_t stream) {
    const float* attn  = (const float*)d_in[0];
    const int*   grids = (const int*)d_in[1];
    float*       out   = (float*)d_out;

    const int B = in_sizes[1] / HW;               // 512
    const float inv_BS = 1.0f / (float)(B * S_DIM);

    hipMemsetAsync(out, 0, sizeof(float) * out_size, stream);
    color_entropy_mfma<<<B, THREADS, 0, stream>>>(attn, grids, out, inv_BS);
}